// Round 2
// baseline (451.379 us; speedup 1.0000x reference)
//
#include <hip/hip_runtime.h>
#include <stdint.h>

typedef unsigned short ushort_t;
typedef __attribute__((ext_vector_type(8))) short short8;
typedef __attribute__((ext_vector_type(4))) short short4v;
typedef __attribute__((ext_vector_type(4))) float f32x4;

#define B_ 4
#define T_ 2048
#define H_ 16
#define DH_ 64
#define DIM_ 1024
#define NE_ 3072
#define LOG2E 1.4426950408889634f

__device__ __forceinline__ ushort_t f2bf(float f) {
  union { float f; uint32_t u; } v; v.f = f;
  uint32_t u = v.u;
  uint32_t r = (u + 0x7FFFu + ((u >> 16) & 1u)) >> 16;  // RNE
  return (ushort_t)r;
}
__device__ __forceinline__ float bf2f(ushort_t u) {
  union { uint32_t u; float f; } v; v.u = ((uint32_t)u) << 16;
  return v.f;
}
__device__ __forceinline__ void gload16(const void* g, void* l) {
  __builtin_amdgcn_global_load_lds(
      (__attribute__((address_space(1))) void*)g,
      (__attribute__((address_space(3))) void*)l, 16, 0, 0);
}

__global__ __launch_bounds__(256)
void cvt_f32_bf16(const float* __restrict__ in, ushort_t* __restrict__ out, long n) {
  const long i = ((long)blockIdx.x * 256 + threadIdx.x) * 4;
  if (i >= n) return;
  const float4 v = *(const float4*)(in + i);
  short4v o;
  o[0] = (short)f2bf(v.x); o[1] = (short)f2bf(v.y);
  o[2] = (short)f2bf(v.z); o[3] = (short)f2bf(v.w);
  *(short4v*)(out + i) = o;
}

// C[m][n] = sum_k A[m][k] * B[n][k]   (both row-major bf16, K contiguous)
// MODE 0: bf16 out to Cb; scale cols with kk==0 by 2^-5 (qkv proj, q-scale folded)
// MODE 1: f32 out to Cf; add bias[n] (f32)
template<int MODE>
__global__ __launch_bounds__(256)
void gemm_bt(const ushort_t* __restrict__ A, const ushort_t* __restrict__ Bm,
             ushort_t* __restrict__ Cb, float* __restrict__ Cf,
             const float* __restrict__ bias, int M, int N, int K, int nb) {
  __shared__ __align__(16) ushort_t Alds[128 * 32];
  __shared__ __align__(16) ushort_t Blds[128 * 32];
  const int tid = threadIdx.x;
  const int wave = tid >> 6, lane = tid & 63;
  const int bid = blockIdx.x;
  const int bm0 = (bid / nb) << 7, bn0 = (bid % nb) << 7;
  const int l4 = lane >> 4, l15 = lane & 15;
  const int srow = lane >> 2;          // 16 rows per 1KB wave-store (64B rows)
  const int scol = (lane & 3) * 8;     // element offset (16B chunks)
  const int wr = (wave >> 1) * 64, wc = (wave & 1) * 64;

  f32x4 acc[4][4];
#pragma unroll
  for (int i = 0; i < 4; ++i)
#pragma unroll
    for (int j = 0; j < 4; ++j) acc[i][j] = {0.f, 0.f, 0.f, 0.f};

  for (int k0 = 0; k0 < K; k0 += 32) {
    __syncthreads();
#pragma unroll
    for (int c = 0; c < 2; ++c) {
      const int r0 = wave * 32 + c * 16;
      gload16(A + (long)(bm0 + r0 + srow) * K + k0 + scol, Alds + r0 * 32);
      gload16(Bm + (long)(bn0 + r0 + srow) * K + k0 + scol, Blds + r0 * 32);
    }
    __syncthreads();
    short8 af[4], bfr[4];
#pragma unroll
    for (int i = 0; i < 4; ++i)
      af[i] = *(const short8*)(Alds + (wr + i * 16 + l15) * 32 + l4 * 8);
#pragma unroll
    for (int j = 0; j < 4; ++j)
      bfr[j] = *(const short8*)(Blds + (wc + j * 16 + l15) * 32 + l4 * 8);
#pragma unroll
    for (int i = 0; i < 4; ++i)
#pragma unroll
      for (int j = 0; j < 4; ++j)
        acc[i][j] = __builtin_amdgcn_mfma_f32_16x16x32_bf16(af[i], bfr[j], acc[i][j], 0, 0, 0);
  }

#pragma unroll
  for (int i = 0; i < 4; ++i) {
    const int row = bm0 + wr + i * 16 + l4 * 4;
#pragma unroll
    for (int j = 0; j < 4; ++j) {
      const int col = bn0 + wc + j * 16 + l15;
      if (MODE == 0) {
        const float mult = (((col >> 4) % 3) == 0) ? 0.03125f : 1.f;
#pragma unroll
        for (int r = 0; r < 4; ++r)
          Cb[(long)(row + r) * N + col] = f2bf(acc[i][j][r] * mult);
      } else {
        const float add = bias[col];
#pragma unroll
        for (int r = 0; r < 4; ++r)
          Cf[(long)(row + r) * N + col] = acc[i][j][r] + add;
      }
    }
  }
}

// qkv[b,t,e] (e = 48d+16kk+h) -> Q[b,h,t,d], K[b,h,t,d], Vt[b,h,d,t]
__global__ __launch_bounds__(256)
void reorg(const ushort_t* __restrict__ qkv, ushort_t* __restrict__ Qh,
           ushort_t* __restrict__ Kh, ushort_t* __restrict__ Vth) {
  __shared__ __align__(16) ushort_t lds[8 * 3080];   // 8 rows, stride 3080 (pad 8)
  const int bid = blockIdx.x;
  const int tt = bid & 255, b = bid >> 8;
  const int t0 = tt * 8;
  const int tid = threadIdx.x;
  const short8* src = (const short8*)(qkv + ((long)(b * T_ + t0)) * NE_);
  short8* dst = (short8*)lds;
  for (int i = tid; i < 8 * 384; i += 256) {
    const int r = i / 384, c = i - r * 384;
    dst[r * 385 + c] = src[i];
  }
  __syncthreads();
  for (int i = tid; i < 16 * 8 * 8; i += 256) {
    const int dblk = i & 7, t = (i >> 3) & 7, h = i >> 6;
    short8 vq, vk;
#pragma unroll
    for (int e = 0; e < 8; ++e) {
      const int d = dblk * 8 + e;
      vq[e] = (short)lds[t * 3080 + d * 48 + h];
      vk[e] = (short)lds[t * 3080 + d * 48 + 16 + h];
    }
    const long o = ((long)((b * H_ + h) * T_) + t0 + t) * DH_ + dblk * 8;
    *(short8*)(Qh + o) = vq;
    *(short8*)(Kh + o) = vk;
  }
  for (int i = tid; i < 16 * 64; i += 256) {
    const int d = i & 63, h = i >> 6;
    short8 v0;
#pragma unroll
    for (int t = 0; t < 8; ++t) v0[t] = (short)lds[t * 3080 + d * 48 + 32 + h];
    const long o = ((long)((b * H_ + h) * DH_) + d) * T_ + t0;
    *(short8*)(Vth + o) = v0;
  }
}

// flash attention: 1 block = (b,h, 64 q rows); 4 waves x 16 rows
__global__ __launch_bounds__(256)
void attn_fwd(const ushort_t* __restrict__ Qh, const ushort_t* __restrict__ Kh,
              const ushort_t* __restrict__ Vth, ushort_t* __restrict__ aout) {
  __shared__ __align__(16) ushort_t Kt[64 * 64];    // [j][d]
  __shared__ __align__(16) ushort_t Vts[64 * 64];   // [d][j]
  __shared__ __align__(16) ushort_t Pb[4][16 * 64]; // per-wave P [row][j]
  const int bid = blockIdx.x;
  const int qt = bid & 31, bh = bid >> 5;
  const int tid = threadIdx.x, wave = tid >> 6, lane = tid & 63;
  const int l4 = lane >> 4, l15 = lane & 15;
  const ushort_t* Qb = Qh + (long)bh * T_ * DH_;
  const ushort_t* Kb = Kh + (long)bh * T_ * DH_;
  const ushort_t* Vb = Vth + (long)bh * DH_ * T_;
  const int q0 = qt * 64 + wave * 16;

  short8 aq[2];
#pragma unroll
  for (int ks = 0; ks < 2; ++ks)
    aq[ks] = *(const short8*)(Qb + (long)(q0 + l15) * DH_ + ks * 32 + l4 * 8);

  float m[4], lsum[4];
  f32x4 o[4];
#pragma unroll
  for (int r = 0; r < 4; ++r) { m[r] = -1e30f; lsum[r] = 0.f; }
#pragma unroll
  for (int nf = 0; nf < 4; ++nf) o[nf] = {0.f, 0.f, 0.f, 0.f};

  const int srow = lane >> 3;          // 8 rows per 1KB wave-store (128B rows)
  const int scol = (lane & 7) * 8;
  ushort_t* pw = &Pb[wave][0];

  for (int j0 = 0; j0 < T_; j0 += 64) {
    __syncthreads();
#pragma unroll
    for (int c = 0; c < 2; ++c) {
      const int r0 = wave * 16 + c * 8;
      gload16(Kb + (long)(j0 + r0 + srow) * DH_ + scol, Kt + r0 * 64);
      gload16(Vb + (long)(r0 + srow) * T_ + j0 + scol, Vts + r0 * 64);
    }
    __syncthreads();

    f32x4 s[4];
#pragma unroll
    for (int jf = 0; jf < 4; ++jf) {
      s[jf] = {0.f, 0.f, 0.f, 0.f};
#pragma unroll
      for (int ks = 0; ks < 2; ++ks) {
        const short8 bk = *(const short8*)(Kt + (jf * 16 + l15) * 64 + ks * 32 + l4 * 8);
        s[jf] = __builtin_amdgcn_mfma_f32_16x16x32_bf16(aq[ks], bk, s[jf], 0, 0, 0);
      }
    }

    float p[4][4];
#pragma unroll
    for (int r = 0; r < 4; ++r) {
      float v = fmaxf(fmaxf(s[0][r], s[1][r]), fmaxf(s[2][r], s[3][r]));
      v = fmaxf(v, __shfl_xor(v, 1));
      v = fmaxf(v, __shfl_xor(v, 2));
      v = fmaxf(v, __shfl_xor(v, 4));
      v = fmaxf(v, __shfl_xor(v, 8));
      const float mnew = fmaxf(m[r], v);
      const float corr = exp2f((m[r] - mnew) * LOG2E);
      float ps = 0.f;
#pragma unroll
      for (int jf = 0; jf < 4; ++jf) {
        const float pv = exp2f((s[jf][r] - mnew) * LOG2E);
        p[jf][r] = pv; ps += pv;
      }
      ps += __shfl_xor(ps, 1);
      ps += __shfl_xor(ps, 2);
      ps += __shfl_xor(ps, 4);
      ps += __shfl_xor(ps, 8);
      lsum[r] = lsum[r] * corr + ps;
      m[r] = mnew;
#pragma unroll
      for (int nf = 0; nf < 4; ++nf) o[nf][r] *= corr;
    }

#pragma unroll
    for (int r = 0; r < 4; ++r)
#pragma unroll
      for (int jf = 0; jf < 4; ++jf)
        pw[(l4 * 4 + r) * 64 + jf * 16 + l15] = f2bf(p[jf][r]);
    __syncthreads();

    short8 ap[2];
#pragma unroll
    for (int ks = 0; ks < 2; ++ks)
      ap[ks] = *(const short8*)(pw + l15 * 64 + ks * 32 + l4 * 8);
#pragma unroll
    for (int nf = 0; nf < 4; ++nf)
#pragma unroll
      for (int ks = 0; ks < 2; ++ks) {
        const short8 bv = *(const short8*)(Vts + (nf * 16 + l15) * 64 + ks * 32 + l4 * 8);
        o[nf] = __builtin_amdgcn_mfma_f32_16x16x32_bf16(ap[ks], bv, o[nf], 0, 0, 0);
      }
  }

  const int b = bh >> 4, h = bh & 15;
#pragma unroll
  for (int r = 0; r < 4; ++r) {
    const float inv = 1.f / lsum[r];
    const int t = q0 + l4 * 4 + r;
#pragma unroll
    for (int nf = 0; nf < 4; ++nf)
      aout[((long)(b * T_ + t)) * DIM_ + h * DH_ + nf * 16 + l15] = f2bf(o[nf][r] * inv);
  }
}

extern "C" void kernel_launch(void* const* d_in, const int* in_sizes, int n_in,
                              void* d_out, int out_size, void* d_ws, size_t ws_size,
                              hipStream_t stream) {
  const float* x_f    = (const float*)d_in[0];
  const float* wqkv_f = (const float*)d_in[1];
  const float* wout_f = (const float*)d_in[2];
  const float* bout_f = (const float*)d_in[3];
  float* out = (float*)d_out;

  // ws layout (bf16 elements):
  // [wqkv_bf 3.1M][wout_bf 1.05M][qkv 25.2M | aout alias][R 25.2M: x_bf then Q/K/Vt]
  ushort_t* wqkv_bf = (ushort_t*)d_ws;
  ushort_t* wout_bf = wqkv_bf + (long)NE_ * DIM_;            // +3,145,728
  ushort_t* qkv     = wout_bf + (long)DIM_ * DIM_;           // +1,048,576
  ushort_t* R       = qkv + (long)B_ * T_ * NE_;             // +25,165,824
  ushort_t* x_bf = R;                                        // dead before reorg writes
  ushort_t* Qh   = R;
  ushort_t* Kh   = R + (long)B_ * H_ * T_ * DH_;
  ushort_t* Vth  = Kh + (long)B_ * H_ * T_ * DH_;
  ushort_t* aout = qkv;  // qkv dead after reorg

  cvt_f32_bf16<<<dim3(8192), dim3(256), 0, stream>>>(x_f, x_bf, (long)B_ * T_ * DIM_);
  cvt_f32_bf16<<<dim3(3072), dim3(256), 0, stream>>>(wqkv_f, wqkv_bf, (long)NE_ * DIM_);
  cvt_f32_bf16<<<dim3(1024), dim3(256), 0, stream>>>(wout_f, wout_bf, (long)DIM_ * DIM_);

  gemm_bt<0><<<dim3((8192 / 128) * (3072 / 128)), dim3(256), 0, stream>>>(
      x_bf, wqkv_bf, qkv, nullptr, nullptr, 8192, 3072, 1024, 3072 / 128);
  reorg<<<dim3(1024), dim3(256), 0, stream>>>(qkv, Qh, Kh, Vth);
  attn_fwd<<<dim3(2048), dim3(256), 0, stream>>>(Qh, Kh, Vth, aout);
  gemm_bt<1><<<dim3((8192 / 128) * (1024 / 128)), dim3(256), 0, stream>>>(
      aout, wout_bf, nullptr, out, bout_f, 8192, 1024, 1024, 1024 / 128);
}

// Round 3
// 263.172 us; speedup vs baseline: 1.7152x; 1.7152x over previous
//
#include <hip/hip_runtime.h>
#include <stdint.h>

typedef unsigned short ushort_t;
typedef __attribute__((ext_vector_type(8))) short short8;
typedef __attribute__((ext_vector_type(4))) short short4v;
typedef __attribute__((ext_vector_type(4))) float f32x4;
typedef __attribute__((ext_vector_type(16))) float f32x16;

#define B_ 4
#define T_ 2048
#define H_ 16
#define DH_ 64
#define DIM_ 1024
#define NE_ 3072
#define LOG2E 1.4426950408889634f

__device__ __forceinline__ ushort_t f2bf(float f) {
  union { float f; uint32_t u; } v; v.f = f;
  uint32_t u = v.u;
  uint32_t r = (u + 0x7FFFu + ((u >> 16) & 1u)) >> 16;  // RNE
  return (ushort_t)r;
}
__device__ __forceinline__ float bf2f(ushort_t u) {
  union { uint32_t u; float f; } v; v.u = ((uint32_t)u) << 16;
  return v.f;
}
__device__ __forceinline__ void gload16(const void* g, void* l) {
  __builtin_amdgcn_global_load_lds(
      (__attribute__((address_space(1))) void*)g,
      (__attribute__((address_space(3))) void*)l, 16, 0, 0);
}
__device__ __forceinline__ uint32_t cvtpk(float a, float b) {
  uint32_t r;
  asm("v_cvt_pk_bf16_f32 %0, %1, %2" : "=v"(r) : "v"(a), "v"(b));
  return r;  // low 16 = bf16(a), high 16 = bf16(b)
}

__global__ __launch_bounds__(256)
void cvt_f32_bf16(const float* __restrict__ in, ushort_t* __restrict__ out, long n) {
  const long i = ((long)blockIdx.x * 256 + threadIdx.x) * 4;
  if (i >= n) return;
  const float4 v = *(const float4*)(in + i);
  short4v o;
  o[0] = (short)f2bf(v.x); o[1] = (short)f2bf(v.y);
  o[2] = (short)f2bf(v.z); o[3] = (short)f2bf(v.w);
  *(short4v*)(out + i) = o;
}

// C[m][n] = sum_k A[m][k] * B[n][k]   (both row-major bf16, K contiguous)
// MODE 0: bf16 out to Cb; scale cols with kk==0 by 2^-5 (qkv proj, q-scale folded)
// MODE 1: f32 out to Cf; add bias[n] (f32)
template<int MODE>
__global__ __launch_bounds__(256)
void gemm_bt(const ushort_t* __restrict__ A, const ushort_t* __restrict__ Bm,
             ushort_t* __restrict__ Cb, float* __restrict__ Cf,
             const float* __restrict__ bias, int M, int N, int K, int nb) {
  __shared__ __align__(16) ushort_t Alds[128 * 32];
  __shared__ __align__(16) ushort_t Blds[128 * 32];
  const int tid = threadIdx.x;
  const int wave = tid >> 6, lane = tid & 63;
  const int bid = blockIdx.x;
  const int bm0 = (bid / nb) << 7, bn0 = (bid % nb) << 7;
  const int l4 = lane >> 4, l15 = lane & 15;
  const int srow = lane >> 2;
  const int scol = (lane & 3) * 8;
  const int wr = (wave >> 1) * 64, wc = (wave & 1) * 64;

  f32x4 acc[4][4];
#pragma unroll
  for (int i = 0; i < 4; ++i)
#pragma unroll
    for (int j = 0; j < 4; ++j) acc[i][j] = {0.f, 0.f, 0.f, 0.f};

  for (int k0 = 0; k0 < K; k0 += 32) {
    __syncthreads();
#pragma unroll
    for (int c = 0; c < 2; ++c) {
      const int r0 = wave * 32 + c * 16;
      gload16(A + (long)(bm0 + r0 + srow) * K + k0 + scol, Alds + r0 * 32);
      gload16(Bm + (long)(bn0 + r0 + srow) * K + k0 + scol, Blds + r0 * 32);
    }
    __syncthreads();
    short8 af[4], bfr[4];
#pragma unroll
    for (int i = 0; i < 4; ++i)
      af[i] = *(const short8*)(Alds + (wr + i * 16 + l15) * 32 + l4 * 8);
#pragma unroll
    for (int j = 0; j < 4; ++j)
      bfr[j] = *(const short8*)(Blds + (wc + j * 16 + l15) * 32 + l4 * 8);
#pragma unroll
    for (int i = 0; i < 4; ++i)
#pragma unroll
      for (int j = 0; j < 4; ++j)
        acc[i][j] = __builtin_amdgcn_mfma_f32_16x16x32_bf16(af[i], bfr[j], acc[i][j], 0, 0, 0);
  }

#pragma unroll
  for (int i = 0; i < 4; ++i) {
    const int row = bm0 + wr + i * 16 + l4 * 4;
#pragma unroll
    for (int j = 0; j < 4; ++j) {
      const int col = bn0 + wc + j * 16 + l15;
      if (MODE == 0) {
        const float mult = (((col >> 4) % 3) == 0) ? 0.03125f : 1.f;
#pragma unroll
        for (int r = 0; r < 4; ++r)
          Cb[(long)(row + r) * N + col] = f2bf(acc[i][j][r] * mult);
      } else {
        const float add = bias[col];
#pragma unroll
        for (int r = 0; r < 4; ++r)
          Cf[(long)(row + r) * N + col] = acc[i][j][r] + add;
      }
    }
  }
}

// qkv[b,t,e] (e = 48d+16kk+h) -> Q[b,h,t,d], K[b,h,t,d], Vt[b,h,d,t]
__global__ __launch_bounds__(256)
void reorg(const ushort_t* __restrict__ qkv, ushort_t* __restrict__ Qh,
           ushort_t* __restrict__ Kh, ushort_t* __restrict__ Vth) {
  __shared__ __align__(16) ushort_t lds[8 * 3080];
  const int bid = blockIdx.x;
  const int tt = bid & 255, b = bid >> 8;
  const int t0 = tt * 8;
  const int tid = threadIdx.x;
  const short8* src = (const short8*)(qkv + ((long)(b * T_ + t0)) * NE_);
  short8* dst = (short8*)lds;
  for (int i = tid; i < 8 * 384; i += 256) {
    const int r = i / 384, c = i - r * 384;
    dst[r * 385 + c] = src[i];
  }
  __syncthreads();
  for (int i = tid; i < 16 * 8 * 8; i += 256) {
    const int dblk = i & 7, t = (i >> 3) & 7, h = i >> 6;
    short8 vq, vk;
#pragma unroll
    for (int e = 0; e < 8; ++e) {
      const int d = dblk * 8 + e;
      vq[e] = (short)lds[t * 3080 + d * 48 + h];
      vk[e] = (short)lds[t * 3080 + d * 48 + 16 + h];
    }
    const long o = ((long)((b * H_ + h) * T_) + t0 + t) * DH_ + dblk * 8;
    *(short8*)(Qh + o) = vq;
    *(short8*)(Kh + o) = vk;
  }
  for (int i = tid; i < 16 * 64; i += 256) {
    const int d = i & 63, h = i >> 6;
    short8 v0;
#pragma unroll
    for (int t = 0; t < 8; ++t) v0[t] = (short)lds[t * 3080 + d * 48 + 32 + h];
    const long o = ((long)((b * H_ + h) * DH_) + d) * T_ + t0;
    *(short8*)(Vth + o) = v0;
  }
}

#define MFMA32(a, b, c) __builtin_amdgcn_mfma_f32_32x32x16_bf16(a, b, c, 0, 0, 0)

// flash attention, swapped-operand 32x32 structure:
//   block = 4 waves x 32 q-rows = 128 q; KV tile 64.
//   S^T = mfma(A=K, B=Q^T): lane owns q = lane&31, regs = kv crow(r,hi)
//   softmax fully in-register (2x shfl_xor(32) merges)
//   P -> bf16 via v_cvt_pk + 2 shfl per ks quad exchange
//   O^T = mfma(A=V^T, B=P^T): O[q][d], q = lane&31 (same layout as softmax state)
// LDS: K[64][64], Vt[64][64] bf16, XOR-swizzled 16B slots (rule 21 both-sides):
//   LDS[r][j] = G[r][j ^ (r&7)], staged by pre-swizzling the global source.
__global__ __launch_bounds__(256, 3)
void attn_fwd2(const ushort_t* __restrict__ Qh, const ushort_t* __restrict__ Kh,
               const ushort_t* __restrict__ Vth, ushort_t* __restrict__ aout) {
  __shared__ __align__(16) ushort_t Kt[64 * 64];
  __shared__ __align__(16) ushort_t Vts[64 * 64];
  // XCD-affine decode: bh % 8 == xcd -> per-XCD KV working set fits L2
  const int bid = blockIdx.x;
  const int xcd = bid & 7, idx = bid >> 3;
  const int bh = xcd + ((idx & 7) << 3);
  const int qb = idx >> 3;  // 0..15
  const int tid = threadIdx.x, wv = tid >> 6, lane = tid & 63;
  const int l31 = lane & 31, hi = lane >> 5, l7 = lane & 7, l8 = lane >> 3;
  const ushort_t* Qb = Qh + (long)bh * T_ * DH_;
  const ushort_t* Kb = Kh + (long)bh * T_ * DH_;
  const ushort_t* Vb = Vth + (long)bh * DH_ * T_;
  const int q = qb * 128 + wv * 32 + l31;  // this lane's q row

  // Q hoisted to registers: qf[s] = Q[q][s*16 + hi*8 .. +8]  (B-fragment layout)
  short8 qf[4];
#pragma unroll
  for (int s = 0; s < 4; ++s)
    qf[s] = *(const short8*)(Qb + (long)q * DH_ + s * 16 + hi * 8);

  f32x16 acc0, acc1;  // O[q][vb*32 + crow(r,hi)]
#pragma unroll
  for (int i = 0; i < 16; ++i) { acc0[i] = 0.f; acc1[i] = 0.f; }
  float m = -1e30f, lsum = 0.f;

  const int r0a = wv * 16;          // rows this wave stages
  const int sl = ((l7 ^ l8) * 8);   // pre-swizzled global slot (elements)

  for (int j0 = 0; j0 < T_; j0 += 64) {
    __syncthreads();
#pragma unroll
    for (int c = 0; c < 2; ++c) {
      const int rr = r0a + c * 8 + l8;
      gload16(Kb + (long)(j0 + rr) * DH_ + sl, Kt + (r0a + c * 8) * 64);
      gload16(Vb + (long)rr * T_ + j0 + sl, Vts + (r0a + c * 8) * 64);
    }
    __syncthreads();

    // S^T = K . Q^T  (two 32-kv blocks)
    f32x16 sb0, sb1;
#pragma unroll
    for (int i = 0; i < 16; ++i) { sb0[i] = 0.f; sb1[i] = 0.f; }
#pragma unroll
    for (int s = 0; s < 4; ++s) {
      const int so = ((2 * s + hi) ^ l7) * 8;
      const short8 k0 = *(const short8*)(Kt + (l31) * 64 + so);
      const short8 k1 = *(const short8*)(Kt + (32 + l31) * 64 + so);
      sb0 = MFMA32(k0, qf[s], sb0);
      sb1 = MFMA32(k1, qf[s], sb1);
    }

    // ---- online softmax, fully in-register ----
    float pmax = sb0[0];
#pragma unroll
    for (int i = 1; i < 16; ++i) pmax = fmaxf(pmax, sb0[i]);
#pragma unroll
    for (int i = 0; i < 16; ++i) pmax = fmaxf(pmax, sb1[i]);
    pmax = fmaxf(pmax, __shfl_xor(pmax, 32));
    if (!__all(pmax - m <= 5.545f)) {  // defer-max: P bounded by 2^8
      const float mnew = fmaxf(m, pmax);
      const float corr = exp2f((m - mnew) * LOG2E);
      lsum *= corr;
#pragma unroll
      for (int i = 0; i < 16; ++i) { acc0[i] *= corr; acc1[i] *= corr; }
      m = mnew;
    }
    const float mb = m * LOG2E;
    float rs = 0.f;
#pragma unroll
    for (int i = 0; i < 16; ++i) {
      sb0[i] = exp2f(fmaf(sb0[i], LOG2E, -mb)); rs += sb0[i];
      sb1[i] = exp2f(fmaf(sb1[i], LOG2E, -mb)); rs += sb1[i];
    }
    lsum += rs + __shfl_xor(rs, 32);

    // ---- P -> bf16 B-fragments (k-window ks*16 + hi*8 + j) ----
    // qw[g] = P-quad words at regs (g&3)*4.. of block g>>2; own g = 2ks+hi,
    // partner quad = partner lane's qw[2ks+hi] = shfl_xor(qw[2ks+1-hi], 32)
    short8 pf[4];
#pragma unroll
    for (int ks = 0; ks < 4; ++ks) {
      const f32x16& S = (ks < 2) ? sb0 : sb1;
      const int rb = (ks & 1) * 8;
      const uint32_t wE0 = cvtpk(S[rb + 0], S[rb + 1]);
      const uint32_t wE1 = cvtpk(S[rb + 2], S[rb + 3]);
      const uint32_t wO0 = cvtpk(S[rb + 4], S[rb + 5]);
      const uint32_t wO1 = cvtpk(S[rb + 6], S[rb + 7]);
      const uint32_t s0 = hi ? wE0 : wO0, s1 = hi ? wE1 : wO1;
      const uint32_t r0 = (uint32_t)__shfl_xor((int)s0, 32);
      const uint32_t r1 = (uint32_t)__shfl_xor((int)s1, 32);
      union { uint32_t u[4]; short8 v; } pk;
      pk.u[0] = hi ? r0 : wE0;
      pk.u[1] = hi ? r1 : wE1;
      pk.u[2] = hi ? wO0 : r0;
      pk.u[3] = hi ? wO1 : r1;
      pf[ks] = pk.v;
    }

    // ---- O^T += V^T . P^T ----
#pragma unroll
    for (int ks = 0; ks < 4; ++ks) {
      const int so = ((2 * ks + hi) ^ l7) * 8;
      const short8 v0 = *(const short8*)(Vts + (l31) * 64 + so);
      const short8 v1 = *(const short8*)(Vts + (32 + l31) * 64 + so);
      acc0 = MFMA32(v0, pf[ks], acc0);
      acc1 = MFMA32(v1, pf[ks], acc1);
    }
  }

  // epilogue: normalize, store (no shuffles: q = lane&31 everywhere)
  const float inv = 1.f / lsum;
  const int b = bh >> 4, h = bh & 15;
  ushort_t* orow = aout + ((long)(b * T_ + q)) * DIM_ + h * DH_;
#pragma unroll
  for (int vb = 0; vb < 2; ++vb)
#pragma unroll
    for (int rg = 0; rg < 4; ++rg) {
      short4v o4;
#pragma unroll
      for (int e = 0; e < 4; ++e) {
        const float val = ((vb == 0) ? acc0[rg * 4 + e] : acc1[rg * 4 + e]) * inv;
        o4[e] = (short)f2bf(val);
      }
      *(short4v*)(orow + vb * 32 + rg * 8 + hi * 4) = o4;
    }
}

extern "C" void kernel_launch(void* const* d_in, const int* in_sizes, int n_in,
                              void* d_out, int out_size, void* d_ws, size_t ws_size,
                              hipStream_t stream) {
  const float* x_f    = (const float*)d_in[0];
  const float* wqkv_f = (const float*)d_in[1];
  const float* wout_f = (const float*)d_in[2];
  const float* bout_f = (const float*)d_in[3];
  float* out = (float*)d_out;

  ushort_t* wqkv_bf = (ushort_t*)d_ws;
  ushort_t* wout_bf = wqkv_bf + (long)NE_ * DIM_;
  ushort_t* qkv     = wout_bf + (long)DIM_ * DIM_;
  ushort_t* R       = qkv + (long)B_ * T_ * NE_;
  ushort_t* x_bf = R;   // dead before reorg writes
  ushort_t* Qh   = R;
  ushort_t* Kh   = R + (long)B_ * H_ * T_ * DH_;
  ushort_t* Vth  = Kh + (long)B_ * H_ * T_ * DH_;
  ushort_t* aout = qkv; // qkv dead after reorg

  cvt_f32_bf16<<<dim3(8192), dim3(256), 0, stream>>>(x_f, x_bf, (long)B_ * T_ * DIM_);
  cvt_f32_bf16<<<dim3(3072), dim3(256), 0, stream>>>(wqkv_f, wqkv_bf, (long)NE_ * DIM_);
  cvt_f32_bf16<<<dim3(1024), dim3(256), 0, stream>>>(wout_f, wout_bf, (long)DIM_ * DIM_);

  gemm_bt<0><<<dim3((8192 / 128) * (3072 / 128)), dim3(256), 0, stream>>>(
      x_bf, wqkv_bf, qkv, nullptr, nullptr, 8192, 3072, 1024, 3072 / 128);
  reorg<<<dim3(1024), dim3(256), 0, stream>>>(qkv, Qh, Kh, Vth);
  attn_fwd2<<<dim3(1024), dim3(256), 0, stream>>>(Qh, Kh, Vth, aout);
  gemm_bt<1><<<dim3((8192 / 128) * (1024 / 128)), dim3(256), 0, stream>>>(
      aout, wout_bf, nullptr, out, bout_f, 8192, 1024, 1024, 1024 / 128);
}

// Round 4
// 233.074 us; speedup vs baseline: 1.9366x; 1.1291x over previous
//
#include <hip/hip_runtime.h>
#include <stdint.h>

typedef unsigned short ushort_t;
typedef __attribute__((ext_vector_type(8))) short short8;
typedef __attribute__((ext_vector_type(4))) short short4v;
typedef __attribute__((ext_vector_type(4))) float f32x4;
typedef __attribute__((ext_vector_type(16))) float f32x16;

#define B_ 4
#define T_ 2048
#define H_ 16
#define DH_ 64
#define DIM_ 1024
#define NE_ 3072
#define LOG2E 1.4426950408889634f

__device__ __forceinline__ ushort_t f2bf(float f) {
  union { float f; uint32_t u; } v; v.f = f;
  uint32_t u = v.u;
  uint32_t r = (u + 0x7FFFu + ((u >> 16) & 1u)) >> 16;  // RNE
  return (ushort_t)r;
}
__device__ __forceinline__ void gload16(const void* g, void* l) {
  __builtin_amdgcn_global_load_lds(
      (__attribute__((address_space(1))) void*)g,
      (__attribute__((address_space(3))) void*)l, 16, 0, 0);
}
__device__ __forceinline__ uint32_t cvtpk(float a, float b) {
  uint32_t r;
  asm("v_cvt_pk_bf16_f32 %0, %1, %2" : "=v"(r) : "v"(a), "v"(b));
  return r;
}
__device__ __forceinline__ float exp2_asm(float x) {
  float r; asm("v_exp_f32 %0, %1" : "=v"(r) : "v"(x)); return r;
}
__device__ __forceinline__ float max3f(float a, float b, float c) {
  float d; asm("v_max3_f32 %0, %1, %2, %3" : "=v"(d) : "v"(a), "v"(b), "v"(c));
  return d;
}

__global__ __launch_bounds__(256)
void cvt_f32_bf16(const float* __restrict__ in, ushort_t* __restrict__ out, long n) {
  const long i = ((long)blockIdx.x * 256 + threadIdx.x) * 4;
  if (i >= n) return;
  const float4 v = *(const float4*)(in + i);
  short4v o;
  o[0] = (short)f2bf(v.x); o[1] = (short)f2bf(v.y);
  o[2] = (short)f2bf(v.z); o[3] = (short)f2bf(v.w);
  *(short4v*)(out + i) = o;
}

// C[m][n] = sum_k A[m][k] * B[n][k]   (both row-major bf16, K contiguous)
// MODE 0: bf16 out; q-cols (kk==0) scaled by LOG2E/32 (scale + log2-domain fold)
// MODE 1: f32 out; add bias[n]
template<int MODE>
__global__ __launch_bounds__(256)
void gemm_bt(const ushort_t* __restrict__ A, const ushort_t* __restrict__ Bm,
             ushort_t* __restrict__ Cb, float* __restrict__ Cf,
             const float* __restrict__ bias, int M, int N, int K, int nb) {
  __shared__ __align__(16) ushort_t Alds[128 * 32];
  __shared__ __align__(16) ushort_t Blds[128 * 32];
  const int tid = threadIdx.x;
  const int wave = tid >> 6, lane = tid & 63;
  const int bid = blockIdx.x;
  const int bm0 = (bid / nb) << 7, bn0 = (bid % nb) << 7;
  const int l4 = lane >> 4, l15 = lane & 15;
  const int srow = lane >> 2;
  const int scol = (lane & 3) * 8;
  const int wr = (wave >> 1) * 64, wc = (wave & 1) * 64;

  f32x4 acc[4][4];
#pragma unroll
  for (int i = 0; i < 4; ++i)
#pragma unroll
    for (int j = 0; j < 4; ++j) acc[i][j] = {0.f, 0.f, 0.f, 0.f};

  for (int k0 = 0; k0 < K; k0 += 32) {
    __syncthreads();
#pragma unroll
    for (int c = 0; c < 2; ++c) {
      const int r0 = wave * 32 + c * 16;
      gload16(A + (long)(bm0 + r0 + srow) * K + k0 + scol, Alds + r0 * 32);
      gload16(Bm + (long)(bn0 + r0 + srow) * K + k0 + scol, Blds + r0 * 32);
    }
    __syncthreads();
    short8 af[4], bfr[4];
#pragma unroll
    for (int i = 0; i < 4; ++i)
      af[i] = *(const short8*)(Alds + (wr + i * 16 + l15) * 32 + l4 * 8);
#pragma unroll
    for (int j = 0; j < 4; ++j)
      bfr[j] = *(const short8*)(Blds + (wc + j * 16 + l15) * 32 + l4 * 8);
#pragma unroll
    for (int i = 0; i < 4; ++i)
#pragma unroll
      for (int j = 0; j < 4; ++j)
        acc[i][j] = __builtin_amdgcn_mfma_f32_16x16x32_bf16(af[i], bfr[j], acc[i][j], 0, 0, 0);
  }

#pragma unroll
  for (int i = 0; i < 4; ++i) {
    const int row = bm0 + wr + i * 16 + l4 * 4;
#pragma unroll
    for (int j = 0; j < 4; ++j) {
      const int col = bn0 + wc + j * 16 + l15;
      if (MODE == 0) {
        // q-scale (dim^-0.5 = 1/32) with LOG2E folded for log2-domain softmax
        const float mult = (((col >> 4) % 3) == 0) ? 0.04508422f : 1.f;
#pragma unroll
        for (int r = 0; r < 4; ++r)
          Cb[(long)(row + r) * N + col] = f2bf(acc[i][j][r] * mult);
      } else {
        const float add = bias[col];
#pragma unroll
        for (int r = 0; r < 4; ++r)
          Cf[(long)(row + r) * N + col] = acc[i][j][r] + add;
      }
    }
  }
}

// qkv[b,t,e] (e = 48d+16kk+h) -> Q[b,h,t,d], K[b,h,t,d], Vt[b,h,d,t]
__global__ __launch_bounds__(256)
void reorg(const ushort_t* __restrict__ qkv, ushort_t* __restrict__ Qh,
           ushort_t* __restrict__ Kh, ushort_t* __restrict__ Vth) {
  __shared__ __align__(16) ushort_t lds[8 * 3080];
  const int bid = blockIdx.x;
  const int tt = bid & 255, b = bid >> 8;
  const int t0 = tt * 8;
  const int tid = threadIdx.x;
  const short8* src = (const short8*)(qkv + ((long)(b * T_ + t0)) * NE_);
  short8* dst = (short8*)lds;
  for (int i = tid; i < 8 * 384; i += 256) {
    const int r = i / 384, c = i - r * 384;
    dst[r * 385 + c] = src[i];
  }
  __syncthreads();
  for (int i = tid; i < 16 * 8 * 8; i += 256) {
    const int dblk = i & 7, t = (i >> 3) & 7, h = i >> 6;
    short8 vq, vk;
#pragma unroll
    for (int e = 0; e < 8; ++e) {
      const int d = dblk * 8 + e;
      vq[e] = (short)lds[t * 3080 + d * 48 + h];
      vk[e] = (short)lds[t * 3080 + d * 48 + 16 + h];
    }
    const long o = ((long)((b * H_ + h) * T_) + t0 + t) * DH_ + dblk * 8;
    *(short8*)(Qh + o) = vq;
    *(short8*)(Kh + o) = vk;
  }
  for (int i = tid; i < 16 * 64; i += 256) {
    const int d = i & 63, h = i >> 6;
    short8 v0;
#pragma unroll
    for (int t = 0; t < 8; ++t) v0[t] = (short)lds[t * 3080 + d * 48 + 32 + h];
    const long o = ((long)((b * H_ + h) * DH_) + d) * T_ + t0;
    *(short8*)(Vth + o) = v0;
  }
}

#define MFMA32(a, b, c) __builtin_amdgcn_mfma_f32_32x32x16_bf16(a, b, c, 0, 0, 0)

// flash attention, swapped-operand 32x32, log2-domain softmax.
// Q pre-scaled by LOG2E/32 => S' = S*LOG2E; QK^T MFMA C-init = -mhat does
// the max-subtraction for free; exp = single v_exp_f32.
__global__ __launch_bounds__(256, 4)
void attn_fwd3(const ushort_t* __restrict__ Qh, const ushort_t* __restrict__ Kh,
               const ushort_t* __restrict__ Vth, ushort_t* __restrict__ aout) {
  __shared__ __align__(16) ushort_t Kt[64 * 64];
  __shared__ __align__(16) ushort_t Vts[64 * 64];
  const int bid = blockIdx.x;
  const int xcd = bid & 7, idx = bid >> 3;
  const int bh = xcd + ((idx & 7) << 3);
  const int qb = idx >> 3;
  const int tid = threadIdx.x, wv = tid >> 6, lane = tid & 63;
  const int l31 = lane & 31, hi = lane >> 5, l7 = lane & 7, l8 = lane >> 3;
  const ushort_t* Qb = Qh + (long)bh * T_ * DH_;
  const ushort_t* Kb = Kh + (long)bh * T_ * DH_;
  const ushort_t* Vb = Vth + (long)bh * DH_ * T_;
  const int q = qb * 128 + wv * 32 + l31;

  short8 qf[4];
#pragma unroll
  for (int s = 0; s < 4; ++s)
    qf[s] = *(const short8*)(Qb + (long)q * DH_ + s * 16 + hi * 8);

  f32x16 acc0, acc1;
#pragma unroll
  for (int i = 0; i < 16; ++i) { acc0[i] = 0.f; acc1[i] = 0.f; }
  float mhat = 0.f, lsum = 0.f;  // log2-domain running max (scores bounded ~|3|)

  const int r0a = wv * 16;
  const int sl = ((l7 ^ l8) * 8);

  for (int j0 = 0; j0 < T_; j0 += 64) {
    __syncthreads();
#pragma unroll
    for (int c = 0; c < 2; ++c) {
      const int rr = r0a + c * 8 + l8;
      gload16(Kb + (long)(j0 + rr) * DH_ + sl, Kt + (r0a + c * 8) * 64);
      gload16(Vb + (long)rr * T_ + j0 + sl, Vts + (r0a + c * 8) * 64);
    }
    __syncthreads();

    // S' - mhat = K.Q^T + C(-mhat)
    const float negm = -mhat;
    f32x16 sb0, sb1;
#pragma unroll
    for (int i = 0; i < 16; ++i) { sb0[i] = negm; sb1[i] = negm; }
    __builtin_amdgcn_s_setprio(1);
#pragma unroll
    for (int s = 0; s < 4; ++s) {
      const int so = ((2 * s + hi) ^ l7) * 8;
      const short8 k0 = *(const short8*)(Kt + (l31) * 64 + so);
      const short8 k1 = *(const short8*)(Kt + (32 + l31) * 64 + so);
      sb0 = MFMA32(k0, qf[s], sb0);
      sb1 = MFMA32(k1, qf[s], sb1);
    }
    __builtin_amdgcn_s_setprio(0);

    // pmax via max3 tree (depth 4)
    float t0 = max3f(sb0[0], sb0[1], sb0[2]);
    float t1 = max3f(sb0[3], sb0[4], sb0[5]);
    float t2 = max3f(sb0[6], sb0[7], sb0[8]);
    float t3 = max3f(sb0[9], sb0[10], sb0[11]);
    float t4 = max3f(sb0[12], sb0[13], sb0[14]);
    float t5 = max3f(sb1[0], sb1[1], sb1[2]);
    float t6 = max3f(sb1[3], sb1[4], sb1[5]);
    float t7 = max3f(sb1[6], sb1[7], sb1[8]);
    float t8 = max3f(sb1[9], sb1[10], sb1[11]);
    float t9 = max3f(sb1[12], sb1[13], sb1[14]);
    float ta = fmaxf(sb0[15], sb1[15]);
    float u0 = max3f(t0, t1, t2);
    float u1 = max3f(t3, t4, t5);
    float u2 = max3f(t6, t7, t8);
    float u3 = max3f(t9, ta, u0);
    float pmax = max3f(u1, u2, u3);
    pmax = fmaxf(pmax, __shfl_xor(pmax, 32));

    if (!__all(pmax <= 8.f)) {  // defer-max: P bounded by 2^8 (rarely taken)
      const float delta = fmaxf(pmax, 0.f);
      const float corr = exp2_asm(-delta);
      lsum *= corr;
#pragma unroll
      for (int i = 0; i < 16; ++i) {
        acc0[i] *= corr; acc1[i] *= corr;
        sb0[i] -= delta; sb1[i] -= delta;
      }
      mhat += delta;
    }

    // p = 2^sb (in place), 4-chain tree sum
    float r0 = 0.f, r1 = 0.f, r2 = 0.f, r3 = 0.f;
#pragma unroll
    for (int i = 0; i < 16; i += 4) {
      sb0[i]     = exp2_asm(sb0[i]);     r0 += sb0[i];
      sb0[i + 1] = exp2_asm(sb0[i + 1]); r1 += sb0[i + 1];
      sb0[i + 2] = exp2_asm(sb0[i + 2]); r2 += sb0[i + 2];
      sb0[i + 3] = exp2_asm(sb0[i + 3]); r3 += sb0[i + 3];
    }
#pragma unroll
    for (int i = 0; i < 16; i += 4) {
      sb1[i]     = exp2_asm(sb1[i]);     r0 += sb1[i];
      sb1[i + 1] = exp2_asm(sb1[i + 1]); r1 += sb1[i + 1];
      sb1[i + 2] = exp2_asm(sb1[i + 2]); r2 += sb1[i + 2];
      sb1[i + 3] = exp2_asm(sb1[i + 3]); r3 += sb1[i + 3];
    }
    float rs = (r0 + r1) + (r2 + r3);
    lsum += rs + __shfl_xor(rs, 32);

    // P -> bf16 B-fragments: cvt_pk + permlane32_swap (no selects)
    short8 pf[4];
#pragma unroll
    for (int ks = 0; ks < 4; ++ks) {
      const f32x16& S = (ks < 2) ? sb0 : sb1;
      const int rb = (ks & 1) * 8;
      uint32_t wE0 = cvtpk(S[rb + 0], S[rb + 1]);
      uint32_t wE1 = cvtpk(S[rb + 2], S[rb + 3]);
      uint32_t wO0 = cvtpk(S[rb + 4], S[rb + 5]);
      uint32_t wO1 = cvtpk(S[rb + 6], S[rb + 7]);
      asm("v_permlane32_swap_b32 %0, %1" : "+v"(wE0), "+v"(wO0));
      asm("v_permlane32_swap_b32 %0, %1" : "+v"(wE1), "+v"(wO1));
      union { uint32_t u[4]; short8 v; } pk;
      pk.u[0] = wE0; pk.u[1] = wE1; pk.u[2] = wO0; pk.u[3] = wO1;
      pf[ks] = pk.v;
    }

    // O^T += V^T . P^T
    __builtin_amdgcn_s_setprio(1);
#pragma unroll
    for (int ks = 0; ks < 4; ++ks) {
      const int so = ((2 * ks + hi) ^ l7) * 8;
      const short8 v0 = *(const short8*)(Vts + (l31) * 64 + so);
      const short8 v1 = *(const short8*)(Vts + (32 + l31) * 64 + so);
      acc0 = MFMA32(v0, pf[ks], acc0);
      acc1 = MFMA32(v1, pf[ks], acc1);
    }
    __builtin_amdgcn_s_setprio(0);
  }

  const float inv = 1.f / lsum;
  const int b = bh >> 4, h = bh & 15;
  ushort_t* orow = aout + ((long)(b * T_ + q)) * DIM_ + h * DH_;
#pragma unroll
  for (int vb = 0; vb < 2; ++vb)
#pragma unroll
    for (int rg = 0; rg < 4; ++rg) {
      short4v o4;
#pragma unroll
      for (int e = 0; e < 4; ++e) {
        const float val = ((vb == 0) ? acc0[rg * 4 + e] : acc1[rg * 4 + e]) * inv;
        o4[e] = (short)f2bf(val);
      }
      *(short4v*)(orow + vb * 32 + rg * 8 + hi * 4) = o4;
    }
}

extern "C" void kernel_launch(void* const* d_in, const int* in_sizes, int n_in,
                              void* d_out, int out_size, void* d_ws, size_t ws_size,
                              hipStream_t stream) {
  const float* x_f    = (const float*)d_in[0];
  const float* wqkv_f = (const float*)d_in[1];
  const float* wout_f = (const float*)d_in[2];
  const float* bout_f = (const float*)d_in[3];
  float* out = (float*)d_out;

  ushort_t* wqkv_bf = (ushort_t*)d_ws;
  ushort_t* wout_bf = wqkv_bf + (long)NE_ * DIM_;
  ushort_t* qkv     = wout_bf + (long)DIM_ * DIM_;
  ushort_t* R       = qkv + (long)B_ * T_ * NE_;
  ushort_t* x_bf = R;
  ushort_t* Qh   = R;
  ushort_t* Kh   = R + (long)B_ * H_ * T_ * DH_;
  ushort_t* Vth  = Kh + (long)B_ * H_ * T_ * DH_;
  ushort_t* aout = qkv;

  cvt_f32_bf16<<<dim3(8192), dim3(256), 0, stream>>>(x_f, x_bf, (long)B_ * T_ * DIM_);
  cvt_f32_bf16<<<dim3(3072), dim3(256), 0, stream>>>(wqkv_f, wqkv_bf, (long)NE_ * DIM_);
  cvt_f32_bf16<<<dim3(1024), dim3(256), 0, stream>>>(wout_f, wout_bf, (long)DIM_ * DIM_);

  gemm_bt<0><<<dim3((8192 / 128) * (3072 / 128)), dim3(256), 0, stream>>>(
      x_bf, wqkv_bf, qkv, nullptr, nullptr, 8192, 3072, 1024, 3072 / 128);
  reorg<<<dim3(1024), dim3(256), 0, stream>>>(qkv, Qh, Kh, Vth);
  attn_fwd3<<<dim3(1024), dim3(256), 0, stream>>>(Qh, Kh, Vth, aout);
  gemm_bt<1><<<dim3((8192 / 128) * (1024 / 128)), dim3(256), 0, stream>>>(
      aout, wout_bf, nullptr, out, bout_f, 8192, 1024, 1024, 1024 / 128);
}

// Round 5
// 229.387 us; speedup vs baseline: 1.9678x; 1.0161x over previous
//
#include <hip/hip_runtime.h>
#include <stdint.h>

typedef unsigned short ushort_t;
typedef __attribute__((ext_vector_type(8))) short short8;
typedef __attribute__((ext_vector_type(4))) short short4v;
typedef __attribute__((ext_vector_type(4))) float f32x4;
typedef __attribute__((ext_vector_type(16))) float f32x16;

#define B_ 4
#define T_ 2048
#define H_ 16
#define DH_ 64
#define DIM_ 1024
#define NE_ 3072
#define LOG2E 1.4426950408889634f

__device__ __forceinline__ ushort_t f2bf(float f) {
  union { float f; uint32_t u; } v; v.f = f;
  uint32_t u = v.u;
  uint32_t r = (u + 0x7FFFu + ((u >> 16) & 1u)) >> 16;  // RNE
  return (ushort_t)r;
}
__device__ __forceinline__ void gload16(const void* g, void* l) {
  __builtin_amdgcn_global_load_lds(
      (__attribute__((address_space(1))) void*)g,
      (__attribute__((address_space(3))) void*)l, 16, 0, 0);
}
__device__ __forceinline__ uint32_t cvtpk(float a, float b) {
  uint32_t r;
  asm("v_cvt_pk_bf16_f32 %0, %1, %2" : "=v"(r) : "v"(a), "v"(b));
  return r;
}
__device__ __forceinline__ float exp2_asm(float x) {
  float r; asm("v_exp_f32 %0, %1" : "=v"(r) : "v"(x)); return r;
}
__device__ __forceinline__ float max3f(float a, float b, float c) {
  float d; asm("v_max3_f32 %0, %1, %2, %3" : "=v"(d) : "v"(a), "v"(b), "v"(c));
  return d;
}
// max over two f32x16 (11 max3 + 1 fmax, depth ~4)
__device__ __forceinline__ float tile_max(const f32x16& a, const f32x16& b) {
  float t0 = max3f(a[0], a[1], a[2]);
  float t1 = max3f(a[3], a[4], a[5]);
  float t2 = max3f(a[6], a[7], a[8]);
  float t3 = max3f(a[9], a[10], a[11]);
  float t4 = max3f(a[12], a[13], a[14]);
  float t5 = max3f(b[0], b[1], b[2]);
  float t6 = max3f(b[3], b[4], b[5]);
  float t7 = max3f(b[6], b[7], b[8]);
  float t8 = max3f(b[9], b[10], b[11]);
  float t9 = max3f(b[12], b[13], b[14]);
  float ta = fmaxf(a[15], b[15]);
  float u0 = max3f(t0, t1, t2);
  float u1 = max3f(t3, t4, t5);
  float u2 = max3f(t6, t7, t8);
  float u3 = max3f(t9, ta, u0);
  return max3f(u1, u2, u3);
}

__global__ __launch_bounds__(256)
void cvt_f32_bf16(const float* __restrict__ in, ushort_t* __restrict__ out, long n) {
  const long i = ((long)blockIdx.x * 256 + threadIdx.x) * 4;
  if (i >= n) return;
  const float4 v = *(const float4*)(in + i);
  short4v o;
  o[0] = (short)f2bf(v.x); o[1] = (short)f2bf(v.y);
  o[2] = (short)f2bf(v.z); o[3] = (short)f2bf(v.w);
  *(short4v*)(out + i) = o;
}

// C[m][n] = sum_k A[m][k] * B[n][k]   (both row-major bf16, K contiguous)
// MODE 0: bf16 out; q-cols (kk==0) scaled by LOG2E/32 (scale + log2-domain fold)
// MODE 1: f32 out; add bias[n]
template<int MODE>
__global__ __launch_bounds__(256)
void gemm_bt(const ushort_t* __restrict__ A, const ushort_t* __restrict__ Bm,
             ushort_t* __restrict__ Cb, float* __restrict__ Cf,
             const float* __restrict__ bias, int M, int N, int K, int nb) {
  __shared__ __align__(16) ushort_t Alds[128 * 32];
  __shared__ __align__(16) ushort_t Blds[128 * 32];
  const int tid = threadIdx.x;
  const int wave = tid >> 6, lane = tid & 63;
  const int bid = blockIdx.x;
  const int bm0 = (bid / nb) << 7, bn0 = (bid % nb) << 7;
  const int l4 = lane >> 4, l15 = lane & 15;
  const int srow = lane >> 2;
  const int scol = (lane & 3) * 8;
  const int wr = (wave >> 1) * 64, wc = (wave & 1) * 64;

  f32x4 acc[4][4];
#pragma unroll
  for (int i = 0; i < 4; ++i)
#pragma unroll
    for (int j = 0; j < 4; ++j) acc[i][j] = {0.f, 0.f, 0.f, 0.f};

  for (int k0 = 0; k0 < K; k0 += 32) {
    __syncthreads();
#pragma unroll
    for (int c = 0; c < 2; ++c) {
      const int r0 = wave * 32 + c * 16;
      gload16(A + (long)(bm0 + r0 + srow) * K + k0 + scol, Alds + r0 * 32);
      gload16(Bm + (long)(bn0 + r0 + srow) * K + k0 + scol, Blds + r0 * 32);
    }
    __syncthreads();
    short8 af[4], bfr[4];
#pragma unroll
    for (int i = 0; i < 4; ++i)
      af[i] = *(const short8*)(Alds + (wr + i * 16 + l15) * 32 + l4 * 8);
#pragma unroll
    for (int j = 0; j < 4; ++j)
      bfr[j] = *(const short8*)(Blds + (wc + j * 16 + l15) * 32 + l4 * 8);
#pragma unroll
    for (int i = 0; i < 4; ++i)
#pragma unroll
      for (int j = 0; j < 4; ++j)
        acc[i][j] = __builtin_amdgcn_mfma_f32_16x16x32_bf16(af[i], bfr[j], acc[i][j], 0, 0, 0);
  }

#pragma unroll
  for (int i = 0; i < 4; ++i) {
    const int row = bm0 + wr + i * 16 + l4 * 4;
#pragma unroll
    for (int j = 0; j < 4; ++j) {
      const int col = bn0 + wc + j * 16 + l15;
      if (MODE == 0) {
        const float mult = (((col >> 4) % 3) == 0) ? 0.04508422f : 1.f;
#pragma unroll
        for (int r = 0; r < 4; ++r)
          Cb[(long)(row + r) * N + col] = f2bf(acc[i][j][r] * mult);
      } else {
        const float add = bias[col];
#pragma unroll
        for (int r = 0; r < 4; ++r)
          Cf[(long)(row + r) * N + col] = acc[i][j][r] + add;
      }
    }
  }
}

// qkv[b,t,e] (e = 48d+16kk+h) -> Q[b,h,t,d], K[b,h,t,d], Vt[b,h,d,t]
__global__ __launch_bounds__(256)
void reorg(const ushort_t* __restrict__ qkv, ushort_t* __restrict__ Qh,
           ushort_t* __restrict__ Kh, ushort_t* __restrict__ Vth) {
  __shared__ __align__(16) ushort_t lds[8 * 3080];
  const int bid = blockIdx.x;
  const int tt = bid & 255, b = bid >> 8;
  const int t0 = tt * 8;
  const int tid = threadIdx.x;
  const short8* src = (const short8*)(qkv + ((long)(b * T_ + t0)) * NE_);
  short8* dst = (short8*)lds;
  for (int i = tid; i < 8 * 384; i += 256) {
    const int r = i / 384, c = i - r * 384;
    dst[r * 385 + c] = src[i];
  }
  __syncthreads();
  for (int i = tid; i < 16 * 8 * 8; i += 256) {
    const int dblk = i & 7, t = (i >> 3) & 7, h = i >> 6;
    short8 vq, vk;
#pragma unroll
    for (int e = 0; e < 8; ++e) {
      const int d = dblk * 8 + e;
      vq[e] = (short)lds[t * 3080 + d * 48 + h];
      vk[e] = (short)lds[t * 3080 + d * 48 + 16 + h];
    }
    const long o = ((long)((b * H_ + h) * T_) + t0 + t) * DH_ + dblk * 8;
    *(short8*)(Qh + o) = vq;
    *(short8*)(Kh + o) = vk;
  }
  for (int i = tid; i < 16 * 64; i += 256) {
    const int d = i & 63, h = i >> 6;
    short8 v0;
#pragma unroll
    for (int t = 0; t < 8; ++t) v0[t] = (short)lds[t * 3080 + d * 48 + 32 + h];
    const long o = ((long)((b * H_ + h) * DH_) + d) * T_ + t0;
    *(short8*)(Vth + o) = v0;
  }
}

#define MFMA32(a, b, c) __builtin_amdgcn_mfma_f32_32x32x16_bf16(a, b, c, 0, 0, 0)

// flash attention v4: 4 waves x 64 q (2 q-streams/wave share K/V fragments),
// KV tile 64, double-buffered LDS, counted vmcnt(4) 2-phase pipeline,
// log2-domain softmax with shared deferred max.
__global__ __launch_bounds__(256, 2)
void attn_fwd4(const ushort_t* __restrict__ Qh, const ushort_t* __restrict__ Kh,
               const ushort_t* __restrict__ Vth, ushort_t* __restrict__ aout) {
  __shared__ __align__(16) ushort_t Kt[2][64 * 64];
  __shared__ __align__(16) ushort_t Vts[2][64 * 64];
  const int bid = blockIdx.x;
  const int xcd = bid & 7, idx = bid >> 3;
  const int bh = xcd + ((idx & 7) << 3);   // 8 bh per XCD -> KV set = 4MB = L2
  const int qsb = idx >> 3;                 // 0..7
  const int tid = threadIdx.x, wv = tid >> 6, lane = tid & 63;
  const int l31 = lane & 31, hi = lane >> 5, l7 = lane & 7, l8 = lane >> 3;
  const ushort_t* Qb = Qh + (long)bh * T_ * DH_;
  const ushort_t* Kb = Kh + (long)bh * T_ * DH_;
  const ushort_t* Vb = Vth + (long)bh * DH_ * T_;
  const int q0 = qsb * 256 + wv * 64;      // this wave covers q0..q0+63

  short8 qfA[4], qfB[4];
#pragma unroll
  for (int s = 0; s < 4; ++s) {
    qfA[s] = *(const short8*)(Qb + (long)(q0 + l31) * DH_ + s * 16 + hi * 8);
    qfB[s] = *(const short8*)(Qb + (long)(q0 + 32 + l31) * DH_ + s * 16 + hi * 8);
  }

  f32x16 accA0, accA1, accB0, accB1;
#pragma unroll
  for (int i = 0; i < 16; ++i) {
    accA0[i] = 0.f; accA1[i] = 0.f; accB0[i] = 0.f; accB1[i] = 0.f;
  }
  float mhat = 0.f, lsumA = 0.f, lsumB = 0.f;

  const int r0a = wv * 16;
  const int sl = ((l7 ^ l8) * 8);   // pre-swizzled global slot

#define STAGE(bufi, jj)                                                        \
  do {                                                                         \
    _Pragma("unroll")                                                          \
    for (int c = 0; c < 2; ++c) {                                              \
      const int rr = r0a + c * 8 + l8;                                         \
      gload16(Kb + (long)((jj) + rr) * DH_ + sl, &Kt[bufi][(r0a + c * 8) * 64]); \
      gload16(Vb + (long)rr * T_ + (jj) + sl, &Vts[bufi][(r0a + c * 8) * 64]); \
    }                                                                          \
  } while (0)

  STAGE(0, 0);
  int buf = 0;

  for (int j0 = 0; j0 < T_; j0 += 64) {
    STAGE(buf ^ 1, (j0 + 64) & (T_ - 1));  // next tile (wraps harmlessly at end)
    asm volatile("s_waitcnt vmcnt(4)" ::: "memory");  // current tile's 4 done
    __builtin_amdgcn_sched_barrier(0);
    __builtin_amdgcn_s_barrier();

    const ushort_t* Ktb = &Kt[buf][0];
    const ushort_t* Vtb = &Vts[buf][0];
    const float negm = -mhat;

    // ---- QK^T both streams ----
    f32x16 sA0, sA1, sB0, sB1;
#pragma unroll
    for (int i = 0; i < 16; ++i) { sA0[i] = negm; sA1[i] = negm; sB0[i] = negm; sB1[i] = negm; }
    __builtin_amdgcn_s_setprio(1);
#pragma unroll
    for (int s = 0; s < 4; ++s) {
      const int so = ((2 * s + hi) ^ l7) * 8;
      const short8 k0 = *(const short8*)(Ktb + (l31) * 64 + so);
      const short8 k1 = *(const short8*)(Ktb + (32 + l31) * 64 + so);
      sA0 = MFMA32(k0, qfA[s], sA0);
      sA1 = MFMA32(k1, qfA[s], sA1);
      sB0 = MFMA32(k0, qfB[s], sB0);
      sB1 = MFMA32(k1, qfB[s], sB1);
    }
    __builtin_amdgcn_s_setprio(0);

    // ---- shared deferred max ----
    float pmax = fmaxf(tile_max(sA0, sA1), tile_max(sB0, sB1));
    pmax = fmaxf(pmax, __shfl_xor(pmax, 32));
    if (!__all(pmax <= 8.f)) {  // rarely taken
      const float delta = fmaxf(pmax, 0.f);
      const float corr = exp2_asm(-delta);
      lsumA *= corr; lsumB *= corr;
#pragma unroll
      for (int i = 0; i < 16; ++i) {
        accA0[i] *= corr; accA1[i] *= corr; accB0[i] *= corr; accB1[i] *= corr;
        sA0[i] -= delta; sA1[i] -= delta; sB0[i] -= delta; sB1[i] -= delta;
      }
      mhat += delta;
    }

    // ---- exp + sums (4-chain trees) ----
    {
      float r0 = 0.f, r1 = 0.f, r2 = 0.f, r3 = 0.f;
#pragma unroll
      for (int i = 0; i < 16; i += 4) {
        sA0[i]     = exp2_asm(sA0[i]);     r0 += sA0[i];
        sA0[i + 1] = exp2_asm(sA0[i + 1]); r1 += sA0[i + 1];
        sA0[i + 2] = exp2_asm(sA0[i + 2]); r2 += sA0[i + 2];
        sA0[i + 3] = exp2_asm(sA0[i + 3]); r3 += sA0[i + 3];
      }
#pragma unroll
      for (int i = 0; i < 16; i += 4) {
        sA1[i]     = exp2_asm(sA1[i]);     r0 += sA1[i];
        sA1[i + 1] = exp2_asm(sA1[i + 1]); r1 += sA1[i + 1];
        sA1[i + 2] = exp2_asm(sA1[i + 2]); r2 += sA1[i + 2];
        sA1[i + 3] = exp2_asm(sA1[i + 3]); r3 += sA1[i + 3];
      }
      float rs = (r0 + r1) + (r2 + r3);
      lsumA += rs + __shfl_xor(rs, 32);
    }
    {
      float r0 = 0.f, r1 = 0.f, r2 = 0.f, r3 = 0.f;
#pragma unroll
      for (int i = 0; i < 16; i += 4) {
        sB0[i]     = exp2_asm(sB0[i]);     r0 += sB0[i];
        sB0[i + 1] = exp2_asm(sB0[i + 1]); r1 += sB0[i + 1];
        sB0[i + 2] = exp2_asm(sB0[i + 2]); r2 += sB0[i + 2];
        sB0[i + 3] = exp2_asm(sB0[i + 3]); r3 += sB0[i + 3];
      }
#pragma unroll
      for (int i = 0; i < 16; i += 4) {
        sB1[i]     = exp2_asm(sB1[i]);     r0 += sB1[i];
        sB1[i + 1] = exp2_asm(sB1[i + 1]); r1 += sB1[i + 1];
        sB1[i + 2] = exp2_asm(sB1[i + 2]); r2 += sB1[i + 2];
        sB1[i + 3] = exp2_asm(sB1[i + 3]); r3 += sB1[i + 3];
      }
      float rs = (r0 + r1) + (r2 + r3);
      lsumB += rs + __shfl_xor(rs, 32);
    }

    // ---- P -> bf16 fragments + PV, stream A then B ----
#define PF_BUILD(pf, S0, S1)                                                   \
  do {                                                                         \
    _Pragma("unroll")                                                          \
    for (int ks = 0; ks < 4; ++ks) {                                           \
      const f32x16& S = (ks < 2) ? (S0) : (S1);                                \
      const int rb = (ks & 1) * 8;                                             \
      uint32_t wE0 = cvtpk(S[rb + 0], S[rb + 1]);                              \
      uint32_t wE1 = cvtpk(S[rb + 2], S[rb + 3]);                              \
      uint32_t wO0 = cvtpk(S[rb + 4], S[rb + 5]);                              \
      uint32_t wO1 = cvtpk(S[rb + 6], S[rb + 7]);                              \
      asm("v_permlane32_swap_b32 %0, %1" : "+v"(wE0), "+v"(wO0));              \
      asm("v_permlane32_swap_b32 %0, %1" : "+v"(wE1), "+v"(wO1));              \
      union { uint32_t u[4]; short8 v; } pk;                                   \
      pk.u[0] = wE0; pk.u[1] = wE1; pk.u[2] = wO0; pk.u[3] = wO1;              \
      pf[ks] = pk.v;                                                           \
    }                                                                          \
  } while (0)

    short8 pfA[4];
    PF_BUILD(pfA, sA0, sA1);
    short8 pfB[4];
    PF_BUILD(pfB, sB0, sB1);

    __builtin_amdgcn_s_setprio(1);
#pragma unroll
    for (int ks = 0; ks < 4; ++ks) {
      const int so = ((2 * ks + hi) ^ l7) * 8;
      const short8 v0 = *(const short8*)(Vtb + (l31) * 64 + so);
      const short8 v1 = *(const short8*)(Vtb + (32 + l31) * 64 + so);
      accA0 = MFMA32(v0, pfA[ks], accA0);
      accA1 = MFMA32(v1, pfA[ks], accA1);
      accB0 = MFMA32(v0, pfB[ks], accB0);
      accB1 = MFMA32(v1, pfB[ks], accB1);
    }
    __builtin_amdgcn_s_setprio(0);

    __builtin_amdgcn_sched_barrier(0);
    __builtin_amdgcn_s_barrier();   // all waves done reading buf before overwrite
    buf ^= 1;
  }

  // ---- epilogue: normalize + store both streams ----
  const int b = bh >> 4, h = bh & 15;
  const float invA = 1.f / lsumA, invB = 1.f / lsumB;
  ushort_t* orowA = aout + ((long)(b * T_ + q0 + l31)) * DIM_ + h * DH_;
  ushort_t* orowB = aout + ((long)(b * T_ + q0 + 32 + l31)) * DIM_ + h * DH_;
#pragma unroll
  for (int vb = 0; vb < 2; ++vb)
#pragma unroll
    for (int rg = 0; rg < 4; ++rg) {
      short4v oA, oB;
#pragma unroll
      for (int e = 0; e < 4; ++e) {
        const float vA = ((vb == 0) ? accA0[rg * 4 + e] : accA1[rg * 4 + e]) * invA;
        const float vB = ((vb == 0) ? accB0[rg * 4 + e] : accB1[rg * 4 + e]) * invB;
        oA[e] = (short)f2bf(vA);
        oB[e] = (short)f2bf(vB);
      }
      *(short4v*)(orowA + vb * 32 + rg * 8 + hi * 4) = oA;
      *(short4v*)(orowB + vb * 32 + rg * 8 + hi * 4) = oB;
    }
}

extern "C" void kernel_launch(void* const* d_in, const int* in_sizes, int n_in,
                              void* d_out, int out_size, void* d_ws, size_t ws_size,
                              hipStream_t stream) {
  const float* x_f    = (const float*)d_in[0];
  const float* wqkv_f = (const float*)d_in[1];
  const float* wout_f = (const float*)d_in[2];
  const float* bout_f = (const float*)d_in[3];
  float* out = (float*)d_out;

  ushort_t* wqkv_bf = (ushort_t*)d_ws;
  ushort_t* wout_bf = wqkv_bf + (long)NE_ * DIM_;
  ushort_t* qkv     = wout_bf + (long)DIM_ * DIM_;
  ushort_t* R       = qkv + (long)B_ * T_ * NE_;
  ushort_t* x_bf = R;
  ushort_t* Qh   = R;
  ushort_t* Kh   = R + (long)B_ * H_ * T_ * DH_;
  ushort_t* Vth  = Kh + (long)B_ * H_ * T_ * DH_;
  ushort_t* aout = qkv;

  cvt_f32_bf16<<<dim3(8192), dim3(256), 0, stream>>>(x_f, x_bf, (long)B_ * T_ * DIM_);
  cvt_f32_bf16<<<dim3(3072), dim3(256), 0, stream>>>(wqkv_f, wqkv_bf, (long)NE_ * DIM_);
  cvt_f32_bf16<<<dim3(1024), dim3(256), 0, stream>>>(wout_f, wout_bf, (long)DIM_ * DIM_);

  gemm_bt<0><<<dim3((8192 / 128) * (3072 / 128)), dim3(256), 0, stream>>>(
      x_bf, wqkv_bf, qkv, nullptr, nullptr, 8192, 3072, 1024, 3072 / 128);
  reorg<<<dim3(1024), dim3(256), 0, stream>>>(qkv, Qh, Kh, Vth);
  attn_fwd4<<<dim3(512), dim3(256), 0, stream>>>(Qh, Kh, Vth, aout);
  gemm_bt<1><<<dim3((8192 / 128) * (1024 / 128)), dim3(256), 0, stream>>>(
      aout, wout_bf, nullptr, out, bout_f, 8192, 1024, 1024, 1024 / 128);
}